// Round 3
// baseline (302.303 us; speedup 1.0000x reference)
//
#include <hip/hip_runtime.h>
#include <hip/hip_bf16.h>
#include <stdint.h>

typedef __bf16 bf16_t;
typedef __bf16 bf16x2 __attribute__((ext_vector_type(2)));
typedef __bf16 bf16x4 __attribute__((ext_vector_type(4)));
typedef __bf16 bf16x8 __attribute__((ext_vector_type(8)));
typedef float f32x4 __attribute__((ext_vector_type(4)));

// Async global->LDS, 16B per lane. LDS dst is wave-uniform base + lane*16.
__device__ __forceinline__ void async_ld16(const bf16_t* g, bf16_t* lds) {
    __builtin_amdgcn_global_load_lds(
        (__attribute__((address_space(1))) void*)g,
        (__attribute__((address_space(3))) void*)lds,
        16, 0, 0);
}

__device__ __forceinline__ void wait_vm0() {
    asm volatile("s_waitcnt vmcnt(0)" ::: "memory");
}

// ---------------- fused prep: X convert + 3 weight transposes ----------------
// R2 rocprof: prep_all was 72.5us at 2.2 TB/s (27% peak), VALU 7% -> latency-
// bound on 4B scalar accesses. Rework: 64x64 tiles, float4 reads (16B/lane),
// bf16x8 writes (16B/lane); LDS float[64][65] (stride 65 => every phase <=2-way
// bank aliasing, which is free per m136). Convert: grid-stride, 32B/thread/iter.

__device__ __forceinline__ void transpose_tile64(
    const float* __restrict__ in, bf16_t* __restrict__ out,
    int R, int C, int tilesX, int tileIdx, int tid, float (*tile)[65])
{
    const int c0 = (tileIdx % tilesX) * 64;
    const int r0 = (tileIdx / tilesX) * 64;
    const int tx4 = (tid & 15) * 4;
    const int ty  = tid >> 4;          // 0..15

    if (c0 + 63 < C) {                 // fully in-bounds: vectorized reads
#pragma unroll
        for (int p = 0; p < 4; ++p) {
            const int row = ty + p * 16;
            const float4 v = *(const float4*)&in[(size_t)(r0 + row) * C + c0 + tx4];
            tile[row][tx4 + 0] = v.x;
            tile[row][tx4 + 1] = v.y;
            tile[row][tx4 + 2] = v.z;
            tile[row][tx4 + 3] = v.w;
        }
    } else {                           // edge tile (Wc cols): scalar + zero-pad
#pragma unroll
        for (int p = 0; p < 4; ++p) {
            const int row = ty + p * 16;
#pragma unroll
            for (int e = 0; e < 4; ++e) {
                const int cc = c0 + tx4 + e;
                tile[row][tx4 + e] = (cc < C) ? in[(size_t)(r0 + row) * C + cc] : 0.f;
            }
        }
    }
    __syncthreads();

    // write-back: thread (px=tid&7, oc=tid>>3) emits bf16x8 along original-row
    // dim. LDS reads tile[px*8+k][oc]: bank=(8*(l&7)+k+(l>>3))%32 -> 2-way, free.
    const int px = tid & 7;
    const int ocb = tid >> 3;          // 0..31
#pragma unroll
    for (int p = 0; p < 2; ++p) {
        const int oc = ocb + p * 32;
        bf16x8 o;
#pragma unroll
        for (int k = 0; k < 8; ++k)
            o[k] = (bf16_t)tile[px * 8 + k][oc];
        *(bf16x8*)&out[(size_t)(c0 + oc) * R + r0 + px * 8] = o;
    }
}

__global__ void prep_all(const float* __restrict__ X, bf16_t* __restrict__ Xb, int n8,
                         const float* __restrict__ W1, bf16_t* __restrict__ W1T,
                         const float* __restrict__ W2, bf16_t* __restrict__ W2T,
                         const float* __restrict__ Wc, bf16_t* __restrict__ WcT,
                         int FEAT, int HID, int NC, int NCP,
                         int nCvt, int t1, int t2)
{
    __shared__ float tile[64][65];
    int bid = blockIdx.x;
    int tid = threadIdx.x;
    if (bid < nCvt) {
        // grid-stride convert: 2x float4 in, 1x bf16x8 out per iter (32B/16B)
        const int stride = nCvt * 256;
        for (int i = bid * 256 + tid; i < n8; i += stride) {
            const float4 a = ((const float4*)X)[i * 2];
            const float4 b = ((const float4*)X)[i * 2 + 1];
            bf16x8 o;
            o[0] = (bf16_t)a.x; o[1] = (bf16_t)a.y; o[2] = (bf16_t)a.z; o[3] = (bf16_t)a.w;
            o[4] = (bf16_t)b.x; o[5] = (bf16_t)b.y; o[6] = (bf16_t)b.z; o[7] = (bf16_t)b.w;
            ((bf16x8*)Xb)[i] = o;
        }
        return;
    }
    bid -= nCvt;
    if (bid < t1) { transpose_tile64(W1, W1T, FEAT, HID, HID / 64, bid, tid, tile); return; }
    bid -= t1;
    if (bid < t2) { transpose_tile64(W2, W2T, HID, HID, HID / 64, bid, tid, tile); return; }
    bid -= t2;
    transpose_tile64(Wc, WcT, HID, NC, NCP / 64, bid, tid, tile);
}

// ---------------- GEMM 128x128, BK=64 + XOR swizzle, split-K, 2-phase --------
// A: [M][K] bf16. B: [N][K] bf16 (weights transposed). P: [S][M][N] fp32.
// 2-phase double-buffer (T3 minimum recipe): issue tile t+1's global_load_lds
// BEFORE computing tile t; single vmcnt(0) + raw s_barrier at END of the step,
// so the ~900cy global latency overlaps the 32 MFMA + 8 ds_read_b128 of the
// compute phase. LDS XOR swizzle: staging fetches pre-swizzled global chunk
// (lane&7)^(row&7); frag reads apply ^(r&7). 0 conflicts measured.
__global__ __launch_bounds__(256, 2) void gemm128_bk64(
    const bf16_t* __restrict__ A, const bf16_t* __restrict__ B,
    float* __restrict__ P, int M, int N, int K, int KC)
{
    __shared__ __align__(16) bf16_t Asm[2][128 * 64];
    __shared__ __align__(16) bf16_t Bsm[2][128 * 64];

    const int tid  = threadIdx.x;
    const int wave = tid >> 6;
    const int lane = tid & 63;
    const int bm = blockIdx.x, bn = blockIdx.y, s = blockIdx.z;

    const int Koff = s * KC;
    const int Kc   = (K - Koff < KC) ? (K - Koff) : KC;   // multiple of 64
    const int nt   = Kc >> 6;

    const bf16_t* Ab = A + (size_t)bm * 128 * K + Koff;
    const bf16_t* Bb = B + (size_t)bn * 128 * K + Koff;

    const int sr = lane >> 3;
    const int sk = ((lane & 7) ^ (sr & 7)) * 8;

    const int wm = (wave >> 1) * 64;
    const int wn = (wave & 1) * 64;
    const int r  = lane & 15;
    const int q  = lane >> 4;

    f32x4 acc[4][4];
#pragma unroll
    for (int i = 0; i < 4; ++i)
#pragma unroll
        for (int j = 0; j < 4; ++j)
            acc[i][j] = f32x4{0.f, 0.f, 0.f, 0.f};

    auto issue = [&](int t, int buf) {
#pragma unroll
        for (int i = 0; i < 4; ++i) {
            const int rb = wave * 32 + i * 8;
            async_ld16(Ab + (size_t)(rb + sr) * K + (t * 64 + sk), &Asm[buf][rb * 64]);
            async_ld16(Bb + (size_t)(rb + sr) * K + (t * 64 + sk), &Bsm[buf][rb * 64]);
        }
    };

    issue(0, 0);
    wait_vm0();
    __builtin_amdgcn_s_barrier();

    int cur = 0;
    for (int t = 0; t < nt; ++t) {
        const bool more = (t + 1 < nt);
        if (more) issue(t + 1, cur ^ 1);   // in flight across compute

#pragma unroll
        for (int rnd = 0; rnd < 2; ++rnd) {
            bf16x8 af[4], bfr[4];
#pragma unroll
            for (int i = 0; i < 4; ++i)
                af[i] = *(const bf16x8*)&Asm[cur][(wm + i * 16 + r) * 64
                                                  + ((rnd * 4 + q) ^ (r & 7)) * 8];
#pragma unroll
            for (int j = 0; j < 4; ++j)
                bfr[j] = *(const bf16x8*)&Bsm[cur][(wn + j * 16 + r) * 64
                                                   + ((rnd * 4 + q) ^ (r & 7)) * 8];
#pragma unroll
            for (int i = 0; i < 4; ++i)
#pragma unroll
                for (int j = 0; j < 4; ++j)
                    acc[i][j] = __builtin_amdgcn_mfma_f32_16x16x32_bf16(af[i], bfr[j], acc[i][j], 0, 0, 0);
        }

        if (more) {
            wait_vm0();
            __builtin_amdgcn_s_barrier();
            cur ^= 1;
        }
    }

    float* Pb = P + ((size_t)s * M + (size_t)bm * 128) * N + (size_t)bn * 128;
    const int r4 = q * 4;
#pragma unroll
    for (int i = 0; i < 4; ++i)
#pragma unroll
        for (int j = 0; j < 4; ++j)
#pragma unroll
            for (int rg = 0; rg < 4; ++rg)
                Pb[(size_t)(wm + i * 16 + r4 + rg) * N + (wn + j * 16 + r)] = acc[i][j][rg];
}

// ---------------- GEMM 64x64, BK=64, full-K, fused bias(+ReLU) epilogue ------
template <bool RELU, typename OutT>
__global__ __launch_bounds__(256, 4) void gemm64_fused(
    const bf16_t* __restrict__ A, const bf16_t* __restrict__ B,
    const float* __restrict__ bias, OutT* __restrict__ out,
    int K, int Nout)
{
    __shared__ __align__(16) bf16_t Asm[2][64 * 64];
    __shared__ __align__(16) bf16_t Bsm[2][64 * 64];

    const int tid  = threadIdx.x;
    const int wave = tid >> 6;
    const int lane = tid & 63;
    const int bm = blockIdx.x, bn = blockIdx.y;

    const bf16_t* Ab = A + (size_t)bm * 64 * K;
    const bf16_t* Bb = B + (size_t)bn * 64 * K;

    const int sr = lane >> 3;
    const int sk = ((lane & 7) ^ (sr & 7)) * 8;

    const int wm = (wave >> 1) * 32;
    const int wn = (wave & 1) * 32;
    const int r  = lane & 15;
    const int q  = lane >> 4;
    const int nt = K >> 6;

    f32x4 acc[2][2];
#pragma unroll
    for (int i = 0; i < 2; ++i)
#pragma unroll
        for (int j = 0; j < 2; ++j)
            acc[i][j] = f32x4{0.f, 0.f, 0.f, 0.f};

    auto issue = [&](int t, int buf) {
#pragma unroll
        for (int i = 0; i < 2; ++i) {
            const int rb = wave * 16 + i * 8;
            async_ld16(Ab + (size_t)(rb + sr) * K + (t * 64 + sk), &Asm[buf][rb * 64]);
            async_ld16(Bb + (size_t)(rb + sr) * K + (t * 64 + sk), &Bsm[buf][rb * 64]);
        }
    };

    issue(0, 0);
    wait_vm0();
    __builtin_amdgcn_s_barrier();

    int cur = 0;
    for (int t = 0; t < nt; ++t) {
        const bool more = (t + 1 < nt);
        if (more) issue(t + 1, cur ^ 1);

#pragma unroll
        for (int rnd = 0; rnd < 2; ++rnd) {
            bf16x8 af[2], bfr[2];
#pragma unroll
            for (int i = 0; i < 2; ++i)
                af[i] = *(const bf16x8*)&Asm[cur][(wm + i * 16 + r) * 64
                                                  + ((rnd * 4 + q) ^ (r & 7)) * 8];
#pragma unroll
            for (int j = 0; j < 2; ++j)
                bfr[j] = *(const bf16x8*)&Bsm[cur][(wn + j * 16 + r) * 64
                                                   + ((rnd * 4 + q) ^ (r & 7)) * 8];
#pragma unroll
            for (int i = 0; i < 2; ++i)
#pragma unroll
                for (int j = 0; j < 2; ++j)
                    acc[i][j] = __builtin_amdgcn_mfma_f32_16x16x32_bf16(af[i], bfr[j], acc[i][j], 0, 0, 0);
        }

        if (more) {
            wait_vm0();
            __builtin_amdgcn_s_barrier();
            cur ^= 1;
        }
    }

    const int r4 = (lane >> 4) * 4;
    const int c  = lane & 15;
#pragma unroll
    for (int i = 0; i < 2; ++i)
#pragma unroll
        for (int j = 0; j < 2; ++j) {
            const int col = bn * 64 + wn + j * 16 + c;
            if (col < Nout) {
                const float bv = bias[col];
#pragma unroll
                for (int rg = 0; rg < 4; ++rg) {
                    const int row = bm * 64 + wm + i * 16 + r4 + rg;
                    float v = acc[i][j][rg] + bv;
                    if (RELU) v = fmaxf(v, 0.f);
                    out[(size_t)row * Nout + col] = (OutT)v;
                }
            }
        }
}

// ---------------- split-K reduction for layer 1 ----------------

template <int S>
__global__ void reduce_relu_bf16_k(const float* __restrict__ P, const float* __restrict__ bias,
                                   bf16_t* __restrict__ h, int MN, int Nm1) {
    int i4 = (blockIdx.x * 256 + threadIdx.x) * 4;
    if (i4 >= MN) return;
    int n = i4 & Nm1;
    float4 a = *(const float4*)(bias + n);
#pragma unroll
    for (int s = 0; s < S; ++s) {
        float4 p = *(const float4*)(P + (size_t)s * MN + i4);
        a.x += p.x; a.y += p.y; a.z += p.z; a.w += p.w;
    }
    a.x = fmaxf(a.x, 0.f); a.y = fmaxf(a.y, 0.f);
    a.z = fmaxf(a.z, 0.f); a.w = fmaxf(a.w, 0.f);
    bf16x4 o = { (bf16_t)a.x, (bf16_t)a.y, (bf16_t)a.z, (bf16_t)a.w };
    *(bf16x4*)(h + i4) = o;
}

// ---------------- launcher ----------------

extern "C" void kernel_launch(void* const* d_in, const int* in_sizes, int n_in,
                              void* d_out, int out_size, void* d_ws, size_t ws_size,
                              hipStream_t stream) {
    const float* X  = (const float*)d_in[0];
    // d_in[1] = batch_indices: group->MLP->ungroup is an identity permutation; unused.
    const float* W1 = (const float*)d_in[2];
    const float* b1 = (const float*)d_in[3];
    const float* W2 = (const float*)d_in[4];
    const float* b2 = (const float*)d_in[5];
    const float* Wc = (const float*)d_in[6];
    const float* bc = (const float*)d_in[7];
    float* out = (float*)d_out;

    const int M    = in_sizes[1];            // 2048
    const int FEAT = in_sizes[0] / M;        // 12544
    const int HID  = in_sizes[3];            // 1024
    const int NC   = in_sizes[7];            // 81
    const int NCP  = 128;                    // padded class dim for MFMA

    char* ws = (char*)d_ws;
    size_t off = 0;
    auto alloc = [&](size_t bytes) {
        char* p = ws + off;
        off += (bytes + 255) & ~(size_t)255;
        return p;
    };
    bf16_t* Xb  = (bf16_t*)alloc((size_t)M * FEAT * 2);
    bf16_t* W1T = (bf16_t*)alloc((size_t)FEAT * HID * 2);
    bf16_t* W2T = (bf16_t*)alloc((size_t)HID * HID * 2);
    bf16_t* WcT = (bf16_t*)alloc((size_t)NCP * HID * 2);
    bf16_t* h1  = (bf16_t*)alloc((size_t)M * HID * 2);
    bf16_t* h2  = (bf16_t*)alloc((size_t)M * HID * 2);
    float*  P   = (float*)(ws + off);

    size_t rem  = ws_size > off ? ws_size - off : 0;
    size_t perS = (size_t)M * HID * 4;
    int S1 = (rem >= 4 * perS) ? 4 : (rem >= 2 * perS) ? 2 : 1;
    int KC1 = ((FEAT / S1 + 63) / 64) * 64;  // 12544/4 = 3136, %64 == 0

    // 1) fused prep: X->bf16 (grid-stride), W1/W2/Wc -> transposed bf16 [N][K]
    int n8   = (M * FEAT) / 8;
    int nCvt = 4096;                          // grid-stride cap (G11)
    int t1 = (FEAT / 64) * (HID / 64);        // 196*16 = 3136
    int t2 = (HID / 64) * (HID / 64);         // 256
    int t3 = (HID / 64) * (NCP / 64);         // 32
    prep_all<<<nCvt + t1 + t2 + t3, 256, 0, stream>>>(
        X, Xb, n8, W1, W1T, W2, W2T, Wc, WcT, FEAT, HID, NC, NCP, nCvt, t1, t2);

    // 2) layer 1: h1 = relu(X@W1 + b1), split-K, 2-phase dbuf
    gemm128_bk64<<<dim3(M / 128, HID / 128, S1), 256, 0, stream>>>(Xb, W1T, P, M, HID, FEAT, KC1);
    switch (S1) {
        case 4: reduce_relu_bf16_k<4><<<(M * HID / 4 + 255) / 256, 256, 0, stream>>>(P, b1, h1, M * HID, HID - 1); break;
        case 2: reduce_relu_bf16_k<2><<<(M * HID / 4 + 255) / 256, 256, 0, stream>>>(P, b1, h1, M * HID, HID - 1); break;
        default: reduce_relu_bf16_k<1><<<(M * HID / 4 + 255) / 256, 256, 0, stream>>>(P, b1, h1, M * HID, HID - 1); break;
    }

    // 3) layer 2: h2 = relu(h1@W2 + b2) — fused epilogue
    gemm64_fused<true, bf16_t><<<dim3(M / 64, HID / 64), 256, 0, stream>>>(h1, W2T, b2, h2, HID, HID);

    // 4) classifier: out = h2@Wc + bc — fused epilogue, fp32 out (n<81)
    gemm64_fused<false, float><<<dim3(M / 64, NCP / 64), 256, 0, stream>>>(h2, WcT, bc, out, HID, NC);
}